// Round 11
// baseline (912.965 us; speedup 1.0000x reference)
//
#include <hip/hip_runtime.h>

// RNNBlock: h_t = relu(x_t @ W + h_{t-1} @ U + b) over reversed T, then
// out = relu(h @ W1 + b1).  B=65536, T=79, F=8, C=DW=256.
//
// R16 = R15 resubmission (R15 hit infra "container failed twice" -- 4th
// occurrence of this flake, Rounds 1/4/8 precedents all benched clean on
// resubmit; re-audit found no defect: 128KB static LDS legal on gfx950,
// barrier discipline identical to twice-passed R7, reg budget ~108V/64A).
//
// R15 = R7 (690us verified) + TWO independent 64-row tiles per block (ILP).
// R14 post-mortem: packed b32 writes ADDED 2.07e7 bank conflicts (2cyc x
// 1.03e7 instrs): b32 conflict unit is the 32-lane phase, and the parity
// pair hit same-bank DIFFERENT dwords; R7's b16 pair writes two halves of
// the SAME dword = merged free.  Write pipe was never the cost -> R7
// epilogue retained exactly.
// R7 model corrected: step 5200 cyc vs LDS-pipe floor ~2650 (256 b128 x 1KB
// / 112B/cyc + writes) = 51% util.  Traffic/elem is at the C_w=32 floor
// (17B/elem; all C_w=64 routes died: R8 spill, R10 no-TLP, R11/12 asm).
// Remaining 2x = latency/convoy: 2 waves/SIMD can't cover ds_read latency
// in one read->MFMA chain, all 8 waves convoy on one barrier per step.
// R15: block owns 128 rows (tiles A,B), hbuf[4][64x256] = 128KB LDS.
// Same bf[17] serves both tiles.  Per step: chainA -> epilogueA (VALU,
// overlaps B reads) -> chainB -> epilogueB.  2 indep dep-chains/wave
// between barriers; barriers per row halve; grid 512 = 2 clean CU rounds.
// x(B) issued mid-chain-A.  V peak ~108-118 <= 128; acc 4x16 = 64 AGPR.
//
// LDS layout per tile (R5-measured conflict-free, R7 XOR-separable):
//   byte(r,c) = (r&63)*512 + (((c>>3) ^ (r&31))<<4) + (c&7)*2
//   read  addr = rbase ^ (kf<<5), rbase = (l31<<9)^(q<<4)^(l31<<4)
//                mf -> +16384 imm, buf -> +32768 imm, tile B -> +65536 base
//   write addr = wbase ^ Kg, Kg = (rr<<9)|(rr<<4), acc1 -> +16384 imm
//
// MFMA v_mfma_f32_32x32x16_f16 layouts (learn_hip verified):
//   A[m][k]: m = lane&31, k = 8*(lane>>5) + j
//   B[k][n]: k = 8*(lane>>5) + j, n = lane&31
//   C/D    : col = lane&31, row = (reg&3) + 8*(reg>>2) + 4*(lane>>5)

#define B_ROWS 65536
#define T_STEPS 79
#define F_IN 8
#define C_DIM 256

typedef _Float16 h16;
typedef __attribute__((ext_vector_type(8))) _Float16 half8;
typedef __attribute__((ext_vector_type(16))) float f32x16;
typedef __attribute__((ext_vector_type(4))) float f32x4;

// B-fragments for the 272x256 augmented weight, this wave's column n.
// rows 0..255 = M (U or W1), 256..263 = Wx (or 0), 264 = bias, 265..271 = 0.
__device__ __forceinline__ void load_bfrags(half8 bf[17],
                                            const float* __restrict__ M,
                                            const float* __restrict__ Wx,
                                            const float* __restrict__ bias,
                                            int n, int q) {
  #pragma unroll
  for (int kf = 0; kf < 16; ++kf) {
    const int k0 = 16 * kf + 8 * q;
    half8 v;
    #pragma unroll
    for (int j = 0; j < 8; ++j)
      v[j] = (h16)M[(size_t)(k0 + j) * C_DIM + n];
    bf[kf] = v;
  }
  half8 v;
  #pragma unroll
  for (int j = 0; j < 8; ++j) v[j] = (h16)0.f;
  if (q == 0) {
    if (Wx) {
      #pragma unroll
      for (int j = 0; j < 8; ++j) v[j] = (h16)Wx[j * C_DIM + n];
    }
  } else {
    v[0] = (h16)bias[n];  // k=264 pairs with A-side constant 1.0
  }
  bf[16] = v;
}

// ---- per-step building blocks (macros so all LDS offsets are immediates) ---

// issue global x loads for tile T's two 32-row halves (q==0 lanes)
#define LOAD_X(lo, hi, XOFF)                                                \
  f32x4 lo[2], hi[2];                                                       \
  if (q == 0) {                                                             \
    _Pragma("unroll") for (int mf = 0; mf < 2; ++mf) {                      \
      const f32x4* xp = (const f32x4*)(xbase + XOFF[mf]);                   \
      lo[mf] = xp[0];                                                       \
      hi[mf] = xp[1];                                                       \
      XOFF[mf] -= F_IN * 4;                                                 \
    }                                                                       \
  }

#define MAKE_XA(xa, lo, hi)                                                 \
  half8 xa[2];                                                              \
  _Pragma("unroll") for (int mf = 0; mf < 2; ++mf) {                        \
    if (q == 0) {                                                           \
      half8 v;                                                              \
      v[0] = (h16)lo[mf][0]; v[1] = (h16)lo[mf][1];                         \
      v[2] = (h16)lo[mf][2]; v[3] = (h16)lo[mf][3];                         \
      v[4] = (h16)hi[mf][0]; v[5] = (h16)hi[mf][1];                         \
      v[6] = (h16)hi[mf][2]; v[7] = (h16)hi[mf][3];                         \
      xa[mf] = v;                                                           \
    } else {                                                                \
      half8 v;                                                              \
      _Pragma("unroll") for (int j = 0; j < 8; ++j) v[j] = (h16)0.f;        \
      v[0] = (h16)1.f; /* bias partner */                                   \
      xa[mf] = v;                                                           \
    }                                                                       \
  }

// R7 epilogue (b16 writes, measured conflict-free): relu -> fp16 -> LDS.
// TB = tile byte base (0 or 65536), WB = dest buffer parity.
#define EPILOGUE(acc0, acc1, TB, WB)                                        \
  _Pragma("unroll") for (int g = 0; g < 16; ++g) {                          \
    const int rr_g = (g & 3) + ((g >> 2) << 3);                             \
    const int Kg = (rr_g << 9) | (rr_g << 4);                               \
    char* const wp = lds + (wbase ^ Kg) + (TB) + (WB)*32768;                \
    *(h16*)(wp) = (h16)fmaxf(acc0[g], 0.f);                                 \
    *(h16*)(wp + 16384) = (h16)fmaxf(acc1[g], 0.f);                         \
  }

// one tile's K-chain: 32 ds_read_b128 + 32 accumulating MFMAs
#define CHAIN(acc0, acc1, TB, RBUF)                                         \
  _Pragma("unroll") for (int kf = 0; kf < 16; ++kf) {                       \
    const char* const rp = lds + (rbase ^ (kf << 5)) + (TB) + (RBUF)*32768; \
    const half8 f0_ = *(const half8*)(rp);                                  \
    acc0 = __builtin_amdgcn_mfma_f32_32x32x16_f16(f0_, bf[kf], acc0,        \
                                                  0, 0, 0);                 \
    const half8 f1_ = *(const half8*)(rp + 16384);                          \
    acc1 = __builtin_amdgcn_mfma_f32_32x32x16_f16(f1_, bf[kf], acc1,        \
                                                  0, 0, 0);                 \
  }

#define STEP(RBUF)                                                         \
  do {                                                                     \
    LOAD_X(alo_, ahi_, xoffA);                                             \
    __syncthreads(); /* h(s-1) writes visible; hides A x-load latency */   \
    MAKE_XA(xaA_, alo_, ahi_);                                             \
    f32x16 aA0_ = __builtin_amdgcn_mfma_f32_32x32x16_f16(                  \
        xaA_[0], bf[16], (f32x16)(0.f), 0, 0, 0);                          \
    f32x16 aA1_ = __builtin_amdgcn_mfma_f32_32x32x16_f16(                  \
        xaA_[1], bf[16], (f32x16)(0.f), 0, 0, 0);                          \
    LOAD_X(blo_, bhi_, xoffB); /* B x-loads hide under chain A */          \
    CHAIN(aA0_, aA1_, 0, RBUF);                                            \
    EPILOGUE(aA0_, aA1_, 0, (RBUF) ^ 1); /* A VALU overlaps B reads */     \
    MAKE_XA(xaB_, blo_, bhi_);                                             \
    f32x16 aB0_ = __builtin_amdgcn_mfma_f32_32x32x16_f16(                  \
        xaB_[0], bf[16], (f32x16)(0.f), 0, 0, 0);                          \
    f32x16 aB1_ = __builtin_amdgcn_mfma_f32_32x32x16_f16(                  \
        xaB_[1], bf[16], (f32x16)(0.f), 0, 0, 0);                          \
    CHAIN(aB0_, aB1_, 65536, RBUF);                                        \
    EPILOGUE(aB0_, aB1_, 65536, (RBUF) ^ 1);                               \
  } while (0)

__global__ __launch_bounds__(512)
__attribute__((amdgpu_waves_per_eu(2, 2)))
void rnn_fused(const float* __restrict__ x, const float* __restrict__ W,
               const float* __restrict__ U, const float* __restrict__ b,
               const float* __restrict__ W1, const float* __restrict__ b1,
               float* __restrict__ out) {
  // [tileA buf0, tileA buf1, tileB buf0, tileB buf1] = 4 x 32 KB = 128 KB
  __shared__ alignas(16) h16 hbuf[4][64 * 256];

  const int tid = threadIdx.x;
  const int lane = tid & 63;
  const int wave = tid >> 6;        // 0..7, owns cols [32w, 32w+32)
  const int l31 = lane & 31;
  const int q = lane >> 5;
  const int row0 = blockIdx.x << 7; // 128 batch rows per block (A:64, B:64)
  const int n = (wave << 5) + l31;  // this lane's output column

  half8 bf[17];
  load_bfrags(bf, U, W, b, n, q);

  char* const lds = (char*)hbuf;

  // XOR-separable base addresses (see header comment)
  const int rbase = (l31 << 9) ^ (q << 4) ^ (l31 << 4);
  const int wbase = (q << 11) ^ (q << 6) ^ ((n >> 3) << 4) ^ ((n & 7) << 1);

  const char* const xbase = (const char*)x;
  int xoffA[2], xoffB[2];
  #pragma unroll
  for (int mf = 0; mf < 2; ++mf) {
    xoffA[mf] = ((row0 + (mf << 5) + l31) * (T_STEPS * F_IN) +
                 (T_STEPS - 1) * F_IN)
                << 2;
    xoffB[mf] = ((row0 + 64 + (mf << 5) + l31) * (T_STEPS * F_IN) +
                 (T_STEPS - 1) * F_IN)
                << 2;
  }

  // ---- s = 0 (t = 78): h0 = 0, no LDS reads, writes buf1, no barrier ----
  {
    LOAD_X(alo_, ahi_, xoffA);
    LOAD_X(blo_, bhi_, xoffB);
    MAKE_XA(xaA_, alo_, ahi_);
    f32x16 aA0_ = __builtin_amdgcn_mfma_f32_32x32x16_f16(
        xaA_[0], bf[16], (f32x16)(0.f), 0, 0, 0);
    f32x16 aA1_ = __builtin_amdgcn_mfma_f32_32x32x16_f16(
        xaA_[1], bf[16], (f32x16)(0.f), 0, 0, 0);
    EPILOGUE(aA0_, aA1_, 0, 1);
    MAKE_XA(xaB_, blo_, bhi_);
    f32x16 aB0_ = __builtin_amdgcn_mfma_f32_32x32x16_f16(
        xaB_[0], bf[16], (f32x16)(0.f), 0, 0, 0);
    f32x16 aB1_ = __builtin_amdgcn_mfma_f32_32x32x16_f16(
        xaB_[1], bf[16], (f32x16)(0.f), 0, 0, 0);
    EPILOGUE(aB0_, aB1_, 65536, 1);
  }

  // ---- s = 1..78 as 39 unrolled pairs: odd s reads buf1, even s buf0 ----
  #pragma unroll 1
  for (int sp = 0; sp < (T_STEPS - 1) / 2; ++sp) {
    STEP(1);
    STEP(0);
  }
  // last step (s=78, even) read buf0 and wrote h(final) into buf1

  // ---- final Dense(256, relu): same GEMM with W1/b1, x rows zeroed ----
  load_bfrags(bf, W1, nullptr, b1, n, q);
  half8 xaf;
  #pragma unroll
  for (int j = 0; j < 8; ++j) xaf[j] = (h16)0.f;
  if (q == 1) xaf[0] = (h16)1.f;

  f32x16 aA0 = __builtin_amdgcn_mfma_f32_32x32x16_f16(
      xaf, bf[16], (f32x16)(0.f), 0, 0, 0);
  f32x16 aA1 = __builtin_amdgcn_mfma_f32_32x32x16_f16(
      xaf, bf[16], (f32x16)(0.f), 0, 0, 0);
  f32x16 aB0 = __builtin_amdgcn_mfma_f32_32x32x16_f16(
      xaf, bf[16], (f32x16)(0.f), 0, 0, 0);
  f32x16 aB1 = __builtin_amdgcn_mfma_f32_32x32x16_f16(
      xaf, bf[16], (f32x16)(0.f), 0, 0, 0);

  __syncthreads();  // h(final) writes visible in buf1 of both tiles

  CHAIN(aA0, aA1, 0, 1);
  CHAIN(aB0, aB1, 65536, 1);

  #pragma unroll
  for (int g = 0; g < 16; ++g) {
    const int rr = (g & 3) + ((g >> 2) << 3) + (q << 2);
    out[(size_t)(row0 + rr) * C_DIM + n] = fmaxf(aA0[g], 0.f);
    out[(size_t)(row0 + 32 + rr) * C_DIM + n] = fmaxf(aA1[g], 0.f);
    out[(size_t)(row0 + 64 + rr) * C_DIM + n] = fmaxf(aB0[g], 0.f);
    out[(size_t)(row0 + 96 + rr) * C_DIM + n] = fmaxf(aB1[g], 0.f);
  }
}

extern "C" void kernel_launch(void* const* d_in, const int* in_sizes, int n_in,
                              void* d_out, int out_size, void* d_ws,
                              size_t ws_size, hipStream_t stream) {
  const float* x  = (const float*)d_in[0];
  const float* W  = (const float*)d_in[1];
  const float* U  = (const float*)d_in[2];
  const float* b  = (const float*)d_in[3];
  const float* W1 = (const float*)d_in[4];
  const float* b1 = (const float*)d_in[5];
  float* out = (float*)d_out;

  rnn_fused<<<B_ROWS / 128, 512, 0, stream>>>(x, W, U, b, W1, b1, out);
}